// Round 13
// baseline (186.654 us; speedup 1.0000x reference)
//
#include <hip/hip_runtime.h>
#include <hip/hip_bf16.h>

#define S_LEN  2048
#define HDIM   1024
#define NHEADS 16
#define HEADD  64
#define BATCH  2
#define MTOT   (BATCH * S_LEN)          // 4096
#define K2EXP  0.04508422f              // log2(e)/32 (folded into Wq/bq)

typedef __attribute__((ext_vector_type(8)))  __bf16 bf16x8;
typedef __attribute__((ext_vector_type(4)))  __bf16 bf16x4;
typedef __attribute__((ext_vector_type(4)))  float  f32x4;
typedef __attribute__((ext_vector_type(16))) float  f32x16;

__device__ __forceinline__ void gload16(const void* g, void* l) {
  __builtin_amdgcn_global_load_lds(
      (const __attribute__((address_space(1))) void*)g,
      (__attribute__((address_space(3))) void*)l, 16, 0, 0);
}
// swizzled LDS read; STRIDE = row stride in bytes, 16B-slot XOR swizzle
template<int STRIDE>
__device__ __forceinline__ bf16x8 lds_rdS(const __bf16* base, int row, int bcol) {
  const char* p = (const char*)base + row * STRIDE + (bcol ^ ((row & (STRIDE / 16 - 1)) << 4));
  return *(const bf16x8*)p;
}
__device__ __forceinline__ unsigned cvtpk_bf16(float lo, float hi) {
  unsigned r;
  asm("v_cvt_pk_bf16_f32 %0, %1, %2" : "=v"(r) : "v"(lo), "v"(hi));
  return r;
}
__device__ __forceinline__ void plswap(unsigned& a, unsigned& b) {
  asm volatile("v_permlane32_swap_b32 %0, %1" : "+v"(a), "+v"(b));
}

// ========================================================= fused prologue ===
// blocks [0,32768): mask -> hi-specific permuted 16-bit tables
//   mbH[hi][b][seg 32][q 2048] u32 (1 MB, L2-resident)
// blocks [32768,33792): W[k][n] f32 -> Wt[n][k] bf16 (Wq scaled by K2EXP)
__global__ __launch_bounds__(256)
void prologue_kernel(const int* __restrict__ mask,
                     const float* __restrict__ Wq, const float* __restrict__ Wk,
                     const float* __restrict__ Wv, const float* __restrict__ Wfc,
                     unsigned* __restrict__ mbH, __bf16* __restrict__ Wt)
{
  __shared__ float T[64][65];
  const int id = blockIdx.x;
  const int tid = threadIdx.x;
  if (id < 32768) {
    const size_t idx = (size_t)id * 256 + tid;
    const int m = mask[idx];
    const unsigned long long bal = __ballot(m != 0);
    const int lane = tid & 63;
    if ((lane & 31) == 0) {
      const int hh = lane >> 5;
      unsigned wlo = 0, whi = 0;
      #pragma unroll
      for (int j = 0; j < 16; ++j) {
        const int kvl = (j & 3) + 8 * (j >> 2) + 4 * hh;
        wlo |= (unsigned)((bal >> kvl) & 1ULL) << j;
        whi |= (unsigned)((bal >> (32 + kvl)) & 1ULL) << j;
      }
      const int b   = (int)(idx >> 22);
      const int qq  = (int)(idx >> 11) & 2047;
      const int seg = ((int)idx & 2047) >> 6;
      mbH[(((size_t)(hh * 2 + b)) * 32 + seg) * S_LEN + qq] = wlo | (whi << 16);
    }
  } else {
    const int f = id - 32768;
    const int z = f >> 8;
    const float* W = (z == 0) ? Wq : (z == 1) ? Wk : (z == 2) ? Wv : Wfc;
    const float sc = (z == 0) ? K2EXP : 1.0f;
    __bf16* O = Wt + (size_t)z * HDIM * HDIM;
    const int k0 = ((f >> 4) & 15) * 64, n0 = (f & 15) * 64;
    const int r  = tid >> 4;
    const int c4 = (tid & 15) * 4;
    #pragma unroll
    for (int p = 0; p < 4; ++p) {
      const int row = r + p * 16;
      const float4 vv = *(const float4*)&W[(size_t)(k0 + row) * HDIM + n0 + c4];
      T[row][c4 + 0] = vv.x; T[row][c4 + 1] = vv.y;
      T[row][c4 + 2] = vv.z; T[row][c4 + 3] = vv.w;
    }
    __syncthreads();
    #pragma unroll
    for (int p = 0; p < 4; ++p) {
      const int n = r + p * 16;
      bf16x4 o;
      #pragma unroll
      for (int i = 0; i < 4; ++i) o[i] = (__bf16)(T[c4 + i][n] * sc);
      *(bf16x4*)&O[(size_t)(n0 + n) * HDIM + k0 + c4] = o;
    }
  }
}

// ============================================================== qkv GEMM ===
// A f32 read DIRECTLY (no cvt pass): reg-staged f32->bf16 + swizzled
// ds_write_b128 (write-XOR == read-XOR). B via gload16. ONE barrier/k-tile:
//   loadA(t+1) -> gloadB(t+1) -> compute(t) -> vmcnt(4) [A drained] ->
//   ds_write A -> vmcnt(0)+lgkmcnt(0) -> barrier
// RAW: each wave drains own A/B + LDS writes before the collective barrier.
// WAR: buf^1's last readers (compute(t-1)) retired at barrier(t-1).
__global__ __launch_bounds__(256)
void qkv_kernel(const float* __restrict__ q, const float* __restrict__ k,
                const float* __restrict__ v, const __bf16* __restrict__ Wt,
                const float* __restrict__ bq, const float* __restrict__ bk,
                const float* __restrict__ bv,
                __bf16* __restrict__ Qb, __bf16* __restrict__ Kb,
                __bf16* __restrict__ Vtg)
{
  __shared__ __bf16 As[2][128][64];
  __shared__ __bf16 Bs[2][128][64];
  const int z = blockIdx.z;
  const float* A    = (z == 0) ? q  : (z == 1) ? k  : v;
  const float* bias = (z == 0) ? bq : (z == 1) ? bk : bv;
  const float bscale = (z == 0) ? K2EXP : 1.0f;
  const __bf16* Wz = Wt + (size_t)z * HDIM * HDIM;

  const int tid = threadIdx.x, lane = tid & 63, w = tid >> 6;
  const int fr = lane & 15, k8 = (lane >> 4) * 8;
  const int wr = w >> 1, wc = w & 1;
  // XCD swizzle (per-z nwg = 256, %8==0): m-bands colocate per XCD
  const int f   = blockIdx.x + 8 * blockIdx.y;
  const int fs  = (f & 7) * 32 + (f >> 3);
  const int m0 = (fs >> 3) * 128, n0 = (fs & 7) * 128;
  const int srow8 = lane >> 3, slot = lane & 7;
  // A reg-stage mapping: thread covers row ar, 32-col half ahf
  const int ar = tid >> 1, ahf = tid & 1;
  const float* asrc = A + (size_t)(m0 + ar) * HDIM + ahf * 32;

  f32x4 acc[4][4] = {};
  float4 areg[8];

  #define Q_LOADA(kt)                                                        \
    { _Pragma("unroll")                                                      \
      for (int i = 0; i < 8; ++i)                                            \
        areg[i] = *(const float4*)(asrc + (kt) * 64 + i * 4); }
  #define Q_STB(kt, bf)                                                      \
    { _Pragma("unroll")                                                      \
      for (int c = 0; c < 4; ++c) {                                          \
        const int rb = w * 32 + c * 8 + srow8;                               \
        gload16(&Wz[(size_t)(n0 + rb) * HDIM + (kt) * 64 + ((slot ^ (rb & 7)) * 8)], \
                (void*)&Bs[bf][rb][0]);                                      \
      } }
  #define Q_WRA(bf)                                                          \
    { _Pragma("unroll")                                                      \
      for (int s = 0; s < 4; ++s) {                                          \
        bf16x8 o;                                                            \
        o[0] = (__bf16)areg[2*s].x;   o[1] = (__bf16)areg[2*s].y;            \
        o[2] = (__bf16)areg[2*s].z;   o[3] = (__bf16)areg[2*s].w;            \
        o[4] = (__bf16)areg[2*s+1].x; o[5] = (__bf16)areg[2*s+1].y;          \
        o[6] = (__bf16)areg[2*s+1].z; o[7] = (__bf16)areg[2*s+1].w;          \
        *(bf16x8*)((char*)&As[bf][ar][0] +                                   \
                   ((ahf * 64 + s * 16) ^ ((ar & 7) << 4))) = o;             \
      } }
  #define Q_COMPUTE(bf)                                                      \
    { _Pragma("unroll")                                                      \
      for (int kk = 0; kk < 64; kk += 32) {                                  \
        bf16x8 a[4], b[4];                                                   \
        _Pragma("unroll")                                                    \
        for (int i = 0; i < 4; ++i)                                          \
          a[i] = lds_rdS<128>(&As[bf][0][0], wr * 64 + i * 16 + fr, (kk + k8) * 2); \
        _Pragma("unroll")                                                    \
        for (int j = 0; j < 4; ++j)                                          \
          b[j] = lds_rdS<128>(&Bs[bf][0][0], wc * 64 + j * 16 + fr, (kk + k8) * 2); \
        _Pragma("unroll")                                                    \
        for (int i = 0; i < 4; ++i)                                          \
          _Pragma("unroll")                                                  \
          for (int j = 0; j < 4; ++j)                                        \
            acc[i][j] = __builtin_amdgcn_mfma_f32_16x16x32_bf16(a[i], b[j], acc[i][j], 0, 0, 0); \
      } }

  // prologue: tile 0
  Q_LOADA(0)
  Q_STB(0, 0)
  asm volatile("s_waitcnt vmcnt(4)" ::: "memory");   // A(0) drained
  Q_WRA(0)
  asm volatile("s_waitcnt vmcnt(0) lgkmcnt(0)" ::: "memory");
  __builtin_amdgcn_s_barrier();

  for (int kt = 0; kt < 15; ++kt) {
    const int buf = kt & 1;
    Q_LOADA(kt + 1)
    Q_STB(kt + 1, buf ^ 1)
    __builtin_amdgcn_s_setprio(1);
    Q_COMPUTE(buf)
    __builtin_amdgcn_s_setprio(0);
    asm volatile("s_waitcnt vmcnt(4)" ::: "memory");  // A(t+1) drained (hidden)
    Q_WRA(buf ^ 1)
    asm volatile("s_waitcnt vmcnt(0) lgkmcnt(0)" ::: "memory");
    __builtin_amdgcn_s_barrier();
  }
  Q_COMPUTE(1)

  const int rg = (lane >> 4) * 4;
  #pragma unroll
  for (int i = 0; i < 4; ++i) {
    #pragma unroll
    for (int j = 0; j < 4; ++j) {
      const int col = n0 + wc * 64 + j * 16 + fr;
      if (z == 2) {
        const int h = col >> 6, hd = col & 63;
        const int row = m0 + wr * 64 + i * 16 + rg;
        const int bq2 = row >> 11, qq = row & 2047;
        bf16x4 o;
        #pragma unroll
        for (int r = 0; r < 4; ++r) o[r] = (__bf16)(acc[i][j][r] + bias[col]);
        *(bf16x4*)&Vtg[(((size_t)bq2 * NHEADS + h) * HEADD + hd) * S_LEN + qq] = o;
      } else {
        __bf16* O = (z == 0) ? Qb : Kb;
        #pragma unroll
        for (int r = 0; r < 4; ++r) {
          const int row = m0 + wr * 64 + i * 16 + rg + r;
          O[(size_t)row * HDIM + col] = (__bf16)(acc[i][j][r] + bias[col] * bscale);
        }
      }
    }
  }
  #undef Q_LOADA
  #undef Q_STB
  #undef Q_WRA
  #undef Q_COMPUTE
}

// ================================================================ fc GEMM ===
// 64x128 tile, BK=64, dbuf, global_load_lds, XCD-swizzled. out f32 + bias
// + resid.
__global__ __launch_bounds__(256)
void fc_kernel(const __bf16* __restrict__ Ab, const __bf16* __restrict__ Wt,
               const float* __restrict__ bias, const float* __restrict__ resid,
               float* __restrict__ Of)
{
  __shared__ __bf16 As[2][64][64];
  __shared__ __bf16 Bs[2][128][64];
  const __bf16* Wz = Wt + (size_t)3 * HDIM * HDIM;
  const int tid = threadIdx.x, lane = tid & 63, w = tid >> 6;
  const int fr = lane & 15, k8 = (lane >> 4) * 8;
  const int wr = w >> 1, wc = w & 1;
  const int f   = blockIdx.x + 8 * blockIdx.y;
  const int fs  = (f & 7) * 64 + (f >> 3);
  const int m0 = (fs >> 3) * 64, n0 = (fs & 7) * 128;
  const int srow8 = lane >> 3, slot = lane & 7;

  f32x4 acc[2][4] = {};

  #define F_STAGE(kt, bf)                                                    \
    { _Pragma("unroll")                                                      \
      for (int c = 0; c < 2; ++c) {                                          \
        const int ra = w * 16 + c * 8 + srow8;                               \
        gload16(&Ab[(size_t)(m0 + ra) * HDIM + (kt) * 64 + ((slot ^ (ra & 7)) * 8)], \
                (void*)&As[bf][ra][0]);                                      \
      }                                                                      \
      _Pragma("unroll")                                                      \
      for (int c = 0; c < 4; ++c) {                                          \
        const int rb = w * 32 + c * 8 + srow8;                               \
        gload16(&Wz[(size_t)(n0 + rb) * HDIM + (kt) * 64 + ((slot ^ (rb & 7)) * 8)], \
                (void*)&Bs[bf][rb][0]);                                      \
      } }
  #define F_COMPUTE(bf)                                                      \
    { _Pragma("unroll")                                                      \
      for (int kk = 0; kk < 64; kk += 32) {                                  \
        bf16x8 a[2], b[4];                                                   \
        _Pragma("unroll")                                                    \
        for (int i = 0; i < 2; ++i)                                          \
          a[i] = lds_rdS<128>(&As[bf][0][0], wr * 32 + i * 16 + fr, (kk + k8) * 2); \
        _Pragma("unroll")                                                    \
        for (int j = 0; j < 4; ++j)                                          \
          b[j] = lds_rdS<128>(&Bs[bf][0][0], wc * 64 + j * 16 + fr, (kk + k8) * 2); \
        _Pragma("unroll")                                                    \
        for (int i = 0; i < 2; ++i)                                          \
          _Pragma("unroll")                                                  \
          for (int j = 0; j < 4; ++j)                                        \
            acc[i][j] = __builtin_amdgcn_mfma_f32_16x16x32_bf16(a[i], b[j], acc[i][j], 0, 0, 0); \
      } }

  F_STAGE(0, 0)
  for (int kt = 0; kt < 15; ++kt) {
    F_STAGE(kt + 1, (kt + 1) & 1)
    asm volatile("s_waitcnt vmcnt(6)" ::: "memory");
    __builtin_amdgcn_s_barrier();
    __builtin_amdgcn_sched_barrier(0);
    __builtin_amdgcn_s_setprio(1);
    F_COMPUTE(kt & 1)
    __builtin_amdgcn_s_setprio(0);
    __builtin_amdgcn_sched_barrier(0);
    __builtin_amdgcn_s_barrier();
  }
  asm volatile("s_waitcnt vmcnt(0)" ::: "memory");
  __builtin_amdgcn_s_barrier();
  F_COMPUTE(1)

  const int rg = (lane >> 4) * 4;
  #pragma unroll
  for (int i = 0; i < 2; ++i) {
    #pragma unroll
    for (int j = 0; j < 4; ++j) {
      const int col = n0 + wc * 64 + j * 16 + fr;
      #pragma unroll
      for (int r = 0; r < 4; ++r) {
        const int row = m0 + wr * 32 + i * 16 + rg + r;
        Of[(size_t)row * HDIM + col] =
            acc[i][j][r] + bias[col] + resid[(size_t)row * HDIM + col];
      }
    }
  }
  #undef F_STAGE
  #undef F_COMPUTE
}

// ============================================================= attention ===
// (r12 verbatim) 8 waves, 128 q/block; wave (qt,kvh): 32q x 32kv-half.
// 3 LDS buffers (48 KB), ONE barrier/tile:
//   vmcnt(0) -> barrier -> stage(t+2) -> QK(t+1) || exp/pack(t) -> PV(t)
__global__ __launch_bounds__(512)
void attn_kernel(const __bf16* __restrict__ Qb, const __bf16* __restrict__ Kb,
                 const __bf16* __restrict__ Vtg, const unsigned* __restrict__ mbH,
                 __bf16* __restrict__ AO)
{
  __shared__ __align__(16) char smem[49152];
  __bf16 (*Ks)[64][64] = (__bf16(*)[64][64])smem;            // 3 x 8 KB
  __bf16 (*Vt)[64][64] = (__bf16(*)[64][64])(smem + 24576);  // 3 x 8 KB

  const int bh = blockIdx.x, b = bh >> 4, h = bh & 15;
  const int tid = threadIdx.x, lane = tid & 63, w = tid >> 6;
  const int fr = lane & 31, hi = lane >> 5;
  const int qt = w >> 1, kvh = w & 1;
  const int qw = blockIdx.y * 128 + qt * 32;
  const int q  = qw + fr;

  bf16x8 qf[4];
  #pragma unroll
  for (int st = 0; st < 4; ++st)
    qf[st] = *(const bf16x8*)&Qb[((size_t)b * S_LEN + q) * HDIM + h * HEADD + st * 16 + hi * 8];

  const int srl = w * 8 + (lane >> 3);
  const int ssw = ((lane & 7) ^ (srl & 7)) * 8;
  const __bf16* ksrc = Kb  + ((size_t)b * S_LEN + srl) * HDIM + h * HEADD + ssw;
  const __bf16* vsrc = Vtg + ((size_t)bh * HEADD + srl) * S_LEN + ssw;
  const unsigned* tbl = mbH + ((size_t)(hi * 2 + b) * 32) * S_LEN + q;

  bf16x8 ones;
  #pragma unroll
  for (int e = 0; e < 8; ++e) ones[e] = (__bf16)1.0f;

  f32x16 o0 = {}, o1 = {}, l_acc = {};

  unsigned mv  = tbl[0];
  unsigned nmA = tbl[S_LEN];
  unsigned nmB = 0;
  gload16(ksrc,             (void*)&Ks[0][w * 8][0]);
  gload16(vsrc,             (void*)&Vt[0][w * 8][0]);
  gload16(ksrc + 64 * HDIM, (void*)&Ks[1][w * 8][0]);
  gload16(vsrc + 64,        (void*)&Vt[1][w * 8][0]);
  asm volatile("s_waitcnt vmcnt(2)" ::: "memory");
  __builtin_amdgcn_s_barrier();

  f32x16 s_cur = {};
  {
    const __bf16* Kb0 = &Ks[0][0][0];
    #pragma unroll
    for (int st = 0; st < 4; ++st)
      s_cur = __builtin_amdgcn_mfma_f32_32x32x16_bf16(
          lds_rdS<128>(Kb0, kvh * 32 + fr, st * 32 + hi * 16), qf[st], s_cur, 0, 0, 0);
  }

  int c0 = 0, c1 = 1, c2 = 2;
  for (int t = 0; t < 32; ++t) {
    asm volatile("s_waitcnt vmcnt(0)" ::: "memory");
    __builtin_amdgcn_s_barrier();
    __builtin_amdgcn_sched_barrier(0);

    if (t < 30) {
      gload16(ksrc + (size_t)(t + 2) * 64 * HDIM, (void*)&Ks[c2][w * 8][0]);
      gload16(vsrc + (size_t)(t + 2) * 64,        (void*)&Vt[c2][w * 8][0]);
      nmB = tbl[(size_t)(t + 2) * S_LEN];
    }

    f32x16 s_nxt = {};
    if (t < 31) {
      const __bf16* Kbn = &Ks[c1][0][0];
      __builtin_amdgcn_s_setprio(1);
      #pragma unroll
      for (int st = 0; st < 4; ++st)
        s_nxt = __builtin_amdgcn_mfma_f32_32x32x16_bf16(
            lds_rdS<128>(Kbn, kvh * 32 + fr, st * 32 + hi * 16), qf[st], s_nxt, 0, 0, 0);
      __builtin_amdgcn_s_setprio(0);
    }

    float pp[16];
    #pragma unroll
    for (int j = 0; j < 16; ++j) {
      const float e = __builtin_amdgcn_exp2f(s_cur[j]);
      const unsigned a = (unsigned)__builtin_amdgcn_sbfe(mv, j + 16 * kvh, 1);
      pp[j] = __uint_as_float(a & __float_as_uint(e));
    }
    bf16x8 pa[2];
    #pragma unroll
    for (int g = 0; g < 2; ++g) {
      const int o = g * 8;
      unsigned x  = cvtpk_bf16(pp[o + 0], pp[o + 1]);
      unsigned x2 = cvtpk_bf16(pp[o + 2], pp[o + 3]);
      unsigned y  = cvtpk_bf16(pp[o + 4], pp[o + 5]);
      unsigned y2 = cvtpk_bf16(pp[o + 6], pp[o + 7]);
      plswap(x, y);
      plswap(x2, y2);
      union { unsigned u[4]; bf16x8 v; } uu;
      uu.u[0] = x; uu.u[1] = x2; uu.u[2] = y; uu.u[3] = y2;
      pa[g] = uu.v;
    }

    {
      const __bf16* Vbc = &Vt[c0][0][0];
      __builtin_amdgcn_s_setprio(1);
      #pragma unroll
      for (int g = 0; g < 2; ++g) {
        const int bcol = kvh * 64 + g * 32 + hi * 16;
        l_acc = __builtin_amdgcn_mfma_f32_32x32x16_bf16(pa[g], ones, l_acc, 0, 0, 0);
        o0 = __builtin_amdgcn_mfma_f32_32x32x16_bf16(
            pa[g], lds_rdS<128>(Vbc, fr,      bcol), o0, 0, 0, 0);
        o1 = __builtin_amdgcn_mfma_f32_32x32x16_bf16(
            pa[g], lds_rdS<128>(Vbc, 32 + fr, bcol), o1, 0, 0, 0);
      }
      __builtin_amdgcn_s_setprio(0);
    }

    mv = nmA; nmA = nmB;
    s_cur = s_nxt;
    const int tmp = c0; c0 = c1; c1 = c2; c2 = tmp;
  }

  __builtin_amdgcn_s_barrier();
  float* sh = (float*)smem;
  const int li = qt * 64 + lane;
  if (kvh) {
    #pragma unroll
    for (int j = 0; j < 16; ++j) {
      sh[(j)      * 256 + li] = o0[j];
      sh[(16 + j) * 256 + li] = o1[j];
      sh[(32 + j) * 256 + li] = l_acc[j];
    }
  }
  __builtin_amdgcn_s_barrier();
  if (!kvh) {
    #pragma unroll
    for (int g = 0; g < 4; ++g) {
      #pragma unroll
      for (int r = 0; r < 4; ++r) {
        const int j = g * 4 + r;
        const float inv = __builtin_amdgcn_rcpf(l_acc[j] + sh[(32 + j) * 256 + li]);
        const int qq = qw + g * 8 + hi * 4 + r;
        AO[((size_t)b * S_LEN + qq) * HDIM + h * HEADD + fr]      =
            (__bf16)((o0[j] + sh[(j) * 256 + li]) * inv);
        AO[((size_t)b * S_LEN + qq) * HDIM + h * HEADD + 32 + fr] =
            (__bf16)((o1[j] + sh[(16 + j) * 256 + li]) * inv);
      }
    }
  }
}

// ============================================================= layernorm ===
__global__ __launch_bounds__(256)
void ln_kernel(float* __restrict__ y, const float* __restrict__ gamma,
               const float* __restrict__ beta)
{
  __shared__ float red[8];
  const int tid = threadIdx.x;
  float* p = y + (size_t)blockIdx.x * HDIM;

  float4 vv = *(const float4*)&p[tid * 4];
  float s  = vv.x + vv.y + vv.z + vv.w;
  float ss = vv.x * vv.x + vv.y * vv.y + vv.z * vv.z + vv.w * vv.w;
  #pragma unroll
  for (int d = 1; d < 64; d <<= 1) {
    s  += __shfl_xor(s, d);
    ss += __shfl_xor(ss, d);
  }
  const int wid = tid >> 6;
  if ((tid & 63) == 0) { red[wid * 2] = s; red[wid * 2 + 1] = ss; }
  __syncthreads();
  s  = red[0] + red[2] + red[4] + red[6];
  ss = red[1] + red[3] + red[5] + red[7];
  const float mean = s * (1.0f / HDIM);
  const float var  = ss * (1.0f / HDIM) - mean * mean;
  const float inv  = rsqrtf(var + 1e-5f);

  const float4 g  = *(const float4*)&gamma[tid * 4];
  const float4 bt = *(const float4*)&beta[tid * 4];
  vv.x = (vv.x - mean) * inv * g.x + bt.x;
  vv.y = (vv.y - mean) * inv * g.y + bt.y;
  vv.z = (vv.z - mean) * inv * g.z + bt.z;
  vv.w = (vv.w - mean) * inv * g.w + bt.w;
  *(float4*)&p[tid * 4] = vv;
}

// ================================================================ launch ===
extern "C" void kernel_launch(void* const* d_in, const int* in_sizes, int n_in,
                              void* d_out, int out_size, void* d_ws, size_t ws_size,
                              hipStream_t stream) {
  const float* q     = (const float*)d_in[0];
  const float* k     = (const float*)d_in[1];
  const float* v     = (const float*)d_in[2];
  const int*   mask  = (const int*)  d_in[3];
  const float* Wq    = (const float*)d_in[4];
  const float* bq    = (const float*)d_in[5];
  const float* Wk    = (const float*)d_in[6];
  const float* bk    = (const float*)d_in[7];
  const float* Wv    = (const float*)d_in[8];
  const float* bv    = (const float*)d_in[9];
  const float* Wfc   = (const float*)d_in[10];
  const float* bfc   = (const float*)d_in[11];
  const float* gamma = (const float*)d_in[12];
  const float* beta  = (const float*)d_in[13];
  float* out = (float*)d_out;

  char* ws = (char*)d_ws;
  const size_t MB16 = (size_t)MTOT * HDIM * 2;     // 8.39 MB per bf16 matrix
  unsigned* mbH = (unsigned*)ws;                   // 1 MB
  __bf16* Wt  = (__bf16*)(ws + (1u << 20));        // 8 MB
  __bf16* Qb  = (__bf16*)(ws + (1u << 20) + 4 * (size_t)HDIM * HDIM * 2);
  __bf16* Kb  = (__bf16*)((char*)Qb + MB16);
  __bf16* Vtg = (__bf16*)((char*)Kb + MB16);
  __bf16* AO  = (__bf16*)((char*)Vtg + MB16);

  const dim3 blk(256);

  prologue_kernel<<<dim3(33792), blk, 0, stream>>>(
      mask, Wq, Wk, Wv, Wfc, mbH, Wt);

  qkv_kernel<<<dim3(8, 32, 3), blk, 0, stream>>>(
      q, k, v, Wt, bq, bk, bv, Qb, Kb, Vtg);

  attn_kernel<<<dim3(BATCH * NHEADS, S_LEN / 128), dim3(512), 0, stream>>>(
      Qb, Kb, Vtg, mbH, AO);

  fc_kernel<<<dim3(8, 64), blk, 0, stream>>>(
      AO, Wt, bfc, q, out);

  ln_kernel<<<dim3(MTOT), blk, 0, stream>>>(out, gamma, beta);
}

// Round 14
// 154.838 us; speedup vs baseline: 1.2055x; 1.2055x over previous
//
#include <hip/hip_runtime.h>
#include <hip/hip_bf16.h>

#define S_LEN  2048
#define HDIM   1024
#define NHEADS 16
#define HEADD  64
#define BATCH  2
#define MTOT   (BATCH * S_LEN)          // 4096
#define K2EXP  0.04508422f              // log2(e)/32 (folded into Wq/bq)

typedef __attribute__((ext_vector_type(8)))  __bf16 bf16x8;
typedef __attribute__((ext_vector_type(4)))  __bf16 bf16x4;
typedef __attribute__((ext_vector_type(4)))  float  f32x4;
typedef __attribute__((ext_vector_type(16))) float  f32x16;

__device__ __forceinline__ void gload16(const void* g, void* l) {
  __builtin_amdgcn_global_load_lds(
      (const __attribute__((address_space(1))) void*)g,
      (__attribute__((address_space(3))) void*)l, 16, 0, 0);
}
// swizzled LDS read; STRIDE = row stride in bytes, 16B-slot XOR swizzle
template<int STRIDE>
__device__ __forceinline__ bf16x8 lds_rdS(const __bf16* base, int row, int bcol) {
  const char* p = (const char*)base + row * STRIDE + (bcol ^ ((row & (STRIDE / 16 - 1)) << 4));
  return *(const bf16x8*)p;
}
__device__ __forceinline__ unsigned cvtpk_bf16(float lo, float hi) {
  unsigned r;
  asm("v_cvt_pk_bf16_f32 %0, %1, %2" : "=v"(r) : "v"(lo), "v"(hi));
  return r;
}
__device__ __forceinline__ void plswap(unsigned& a, unsigned& b) {
  asm volatile("v_permlane32_swap_b32 %0, %1" : "+v"(a), "+v"(b));
}

// ========================================================= fused prologue ===
// blocks [0,6144): f32->bf16 cvt of q/k/v
// blocks [6144,38912): mask -> hi-specific permuted 16-bit tables (1 MB)
// blocks [38912,39936): W[k][n] f32 -> Wt[n][k] bf16 (Wq scaled by K2EXP)
__global__ __launch_bounds__(256)
void prologue_kernel(const float* __restrict__ q, const float* __restrict__ k,
                     const float* __restrict__ v, const int* __restrict__ mask,
                     const float* __restrict__ Wq, const float* __restrict__ Wk,
                     const float* __restrict__ Wv, const float* __restrict__ Wfc,
                     __bf16* __restrict__ Qc, __bf16* __restrict__ Kc,
                     __bf16* __restrict__ Vc, unsigned* __restrict__ mbH,
                     __bf16* __restrict__ Wt)
{
  __shared__ float T[64][65];
  const int id = blockIdx.x;
  const int tid = threadIdx.x;
  if (id < 6144) {
    const int z = id >> 11, blk = id & 2047;
    const float* src = (z == 0) ? q : (z == 1) ? k : v;
    __bf16* dst = (z == 0) ? Qc : (z == 1) ? Kc : Vc;
    const size_t i = ((size_t)blk * 256 + tid) * 8;
    const float4 a = *(const float4*)&src[i];
    const float4 c = *(const float4*)&src[i + 4];
    bf16x8 o;
    o[0] = (__bf16)a.x; o[1] = (__bf16)a.y; o[2] = (__bf16)a.z; o[3] = (__bf16)a.w;
    o[4] = (__bf16)c.x; o[5] = (__bf16)c.y; o[6] = (__bf16)c.z; o[7] = (__bf16)c.w;
    *(bf16x8*)&dst[i] = o;
  } else if (id < 38912) {
    const size_t idx = (size_t)(id - 6144) * 256 + tid;
    const int m = mask[idx];
    const unsigned long long bal = __ballot(m != 0);
    const int lane = tid & 63;
    if ((lane & 31) == 0) {
      const int hh = lane >> 5;
      unsigned wlo = 0, whi = 0;
      #pragma unroll
      for (int j = 0; j < 16; ++j) {
        const int kvl = (j & 3) + 8 * (j >> 2) + 4 * hh;
        wlo |= (unsigned)((bal >> kvl) & 1ULL) << j;
        whi |= (unsigned)((bal >> (32 + kvl)) & 1ULL) << j;
      }
      const int b   = (int)(idx >> 22);
      const int qq  = (int)(idx >> 11) & 2047;
      const int seg = ((int)idx & 2047) >> 6;
      mbH[(((size_t)(hh * 2 + b)) * 32 + seg) * S_LEN + qq] = wlo | (whi << 16);
    }
  } else {
    const int f = id - 38912;
    const int z = f >> 8;
    const float* W = (z == 0) ? Wq : (z == 1) ? Wk : (z == 2) ? Wv : Wfc;
    const float sc = (z == 0) ? K2EXP : 1.0f;
    __bf16* O = Wt + (size_t)z * HDIM * HDIM;
    const int k0 = ((f >> 4) & 15) * 64, n0 = (f & 15) * 64;
    const int r  = tid >> 4;
    const int c4 = (tid & 15) * 4;
    #pragma unroll
    for (int p = 0; p < 4; ++p) {
      const int row = r + p * 16;
      const float4 vv = *(const float4*)&W[(size_t)(k0 + row) * HDIM + n0 + c4];
      T[row][c4 + 0] = vv.x; T[row][c4 + 1] = vv.y;
      T[row][c4 + 2] = vv.z; T[row][c4 + 3] = vv.w;
    }
    __syncthreads();
    #pragma unroll
    for (int p = 0; p < 4; ++p) {
      const int n = r + p * 16;
      bf16x4 o;
      #pragma unroll
      for (int i = 0; i < 4; ++i) o[i] = (__bf16)(T[c4 + i][n] * sc);
      *(bf16x4*)&O[(size_t)(n0 + n) * HDIM + k0 + c4] = o;
    }
  }
}

// ================================================================== GEMM ===
// BMT x 128 tile, BK=64, dbuf, global_load_lds. Caller supplies m0/n0.
// MODE 0: out bf16 (+bias*bscale). MODE 1: out f32 (+bias+resid).
// MODE 2: out = V^T per head (bf16) for attention.
template<int MODE, int BMT>
__device__ __forceinline__ void gemm_body(
    __bf16* As, __bf16* Bs, int m0, int n0,
    const __bf16* __restrict__ A, const __bf16* __restrict__ Wt,
    const float* __restrict__ bias, float bscale,
    const float* __restrict__ resid,
    __bf16* __restrict__ Ob, float* __restrict__ Of, __bf16* __restrict__ Vtg)
{
  constexpr int AI = BMT / 32;          // wave M-tiles (4 or 2)
  const int tid = threadIdx.x, lane = tid & 63, w = tid >> 6;
  const int fr = lane & 15, k8 = (lane >> 4) * 8;
  const int wr = w >> 1, wc = w & 1;
  const int srow8 = lane >> 3, slot = lane & 7;

  f32x4 acc[AI][4] = {};

  #define G_STAGE(kt, bf)                                                    \
    {                                                                        \
      _Pragma("unroll")                                                      \
      for (int c = 0; c < AI; ++c) {                                         \
        const int ra = w * (BMT / 4) + c * 8 + srow8;                        \
        gload16(&A[(size_t)(m0 + ra) * HDIM + (kt) * 64 + ((slot ^ (ra & 7)) * 8)], \
                (void*)&As[((bf) * BMT + ra) * 64]);                         \
      }                                                                      \
      _Pragma("unroll")                                                      \
      for (int c = 0; c < 4; ++c) {                                          \
        const int rb = w * 32 + c * 8 + srow8;                               \
        gload16(&Wt[(size_t)(n0 + rb) * HDIM + (kt) * 64 + ((slot ^ (rb & 7)) * 8)], \
                (void*)&Bs[((bf) * 128 + rb) * 64]);                         \
      }                                                                      \
    }

  #define G_COMPUTE(bf)                                                      \
    {                                                                        \
      _Pragma("unroll")                                                      \
      for (int kk = 0; kk < 64; kk += 32) {                                  \
        bf16x8 a[AI], b[4];                                                  \
        _Pragma("unroll")                                                    \
        for (int i = 0; i < AI; ++i)                                         \
          a[i] = lds_rdS<128>(&As[(bf) * BMT * 64], wr * (BMT / 2) + i * 16 + fr, (kk + k8) * 2); \
        _Pragma("unroll")                                                    \
        for (int j = 0; j < 4; ++j)                                          \
          b[j] = lds_rdS<128>(&Bs[(bf) * 128 * 64], wc * 64 + j * 16 + fr, (kk + k8) * 2); \
        _Pragma("unroll")                                                    \
        for (int i = 0; i < AI; ++i)                                         \
          _Pragma("unroll")                                                  \
          for (int j = 0; j < 4; ++j)                                        \
            acc[i][j] = __builtin_amdgcn_mfma_f32_16x16x32_bf16(a[i], b[j], acc[i][j], 0, 0, 0); \
      }                                                                      \
    }

  G_STAGE(0, 0)
  for (int kt = 0; kt < 15; ++kt) {
    G_STAGE(kt + 1, (kt + 1) & 1)
    if constexpr (BMT == 128) asm volatile("s_waitcnt vmcnt(8)" ::: "memory");
    else                      asm volatile("s_waitcnt vmcnt(6)" ::: "memory");
    __builtin_amdgcn_s_barrier();
    __builtin_amdgcn_sched_barrier(0);
    __builtin_amdgcn_s_setprio(1);
    G_COMPUTE(kt & 1)
    __builtin_amdgcn_s_setprio(0);
    __builtin_amdgcn_sched_barrier(0);
    __builtin_amdgcn_s_barrier();
  }
  asm volatile("s_waitcnt vmcnt(0)" ::: "memory");
  __builtin_amdgcn_s_barrier();
  G_COMPUTE(1)

  const int rg = (lane >> 4) * 4;
  #pragma unroll
  for (int i = 0; i < AI; ++i) {
    #pragma unroll
    for (int j = 0; j < 4; ++j) {
      const int col = n0 + wc * 64 + j * 16 + fr;
      if constexpr (MODE == 2) {
        const int h = col >> 6, hd = col & 63;
        const int row = m0 + wr * (BMT / 2) + i * 16 + rg;
        const int bq = row >> 11, qq = row & 2047;
        bf16x4 o;
        #pragma unroll
        for (int r = 0; r < 4; ++r) o[r] = (__bf16)(acc[i][j][r] + bias[col]);
        *(bf16x4*)&Vtg[(((size_t)bq * NHEADS + h) * HEADD + hd) * S_LEN + qq] = o;
      } else {
        #pragma unroll
        for (int r = 0; r < 4; ++r) {
          const int row = m0 + wr * (BMT / 2) + i * 16 + rg + r;
          if constexpr (MODE == 0) {
            Ob[(size_t)row * HDIM + col] = (__bf16)(acc[i][j][r] + bias[col] * bscale);
          } else {
            Of[(size_t)row * HDIM + col] =
                acc[i][j][r] + bias[col] + resid[(size_t)row * HDIM + col];
          }
        }
      }
    }
  }
  #undef G_STAGE
  #undef G_COMPUTE
}

// qkv: 1-D grid 768, chunked bijective XCD swizzle spanning z: each XCD owns
// 96 consecutive (z, m-band, n) chunks -> ~one z's A-panel (3MB) + one Wt
// (2MB) = 5MB/XCD (vs 9MB interleaved) -> better L2 hit rate.
__global__ __launch_bounds__(256)
void qkv_kernel(const __bf16* __restrict__ Qc, const __bf16* __restrict__ Kc,
                const __bf16* __restrict__ Vc, const __bf16* __restrict__ Wt,
                const float* __restrict__ bq, const float* __restrict__ bk,
                const float* __restrict__ bv,
                __bf16* __restrict__ Qb, __bf16* __restrict__ Kb,
                __bf16* __restrict__ Vtg)
{
  __shared__ __bf16 smem[2 * 128 * 64 * 2];
  __bf16* As = smem;
  __bf16* Bs = smem + 2 * 128 * 64;
  const int fid = blockIdx.x;                       // 0..767
  const int chunk = (fid & 7) * 96 + (fid >> 3);    // bijective (768 % 8 == 0)
  const int z  = chunk >> 8;                        // 0..2
  const int fs = chunk & 255;
  const int m0 = (fs >> 3) * 128, n0 = (fs & 7) * 128;
  if (z == 2) {
    gemm_body<2, 128>(As, Bs, m0, n0, Vc, Wt + (size_t)2 * HDIM * HDIM, bv, 1.0f,
                      nullptr, nullptr, nullptr, Vtg);
  } else if (z == 1) {
    gemm_body<0, 128>(As, Bs, m0, n0, Kc, Wt + (size_t)HDIM * HDIM,
                      bk, 1.0f, nullptr, Kb, nullptr, nullptr);
  } else {
    gemm_body<0, 128>(As, Bs, m0, n0, Qc, Wt,
                      bq, K2EXP, nullptr, Qb, nullptr, nullptr);
  }
}

__global__ __launch_bounds__(256)
void fc_kernel(const __bf16* __restrict__ A, const __bf16* __restrict__ Wt,
               const float* __restrict__ bias, const float* __restrict__ resid,
               float* __restrict__ Of)
{
  __shared__ __bf16 smem[2 * 64 * 64 + 2 * 128 * 64];
  __bf16* As = smem;
  __bf16* Bs = smem + 2 * 64 * 64;
  const int f   = blockIdx.x + 8 * blockIdx.y;      // grid (8,64) = 512
  const int fs  = (f & 7) * 64 + (f >> 3);
  const int m0 = (fs >> 3) * 64, n0 = (fs & 7) * 128;
  gemm_body<1, 64>(As, Bs, m0, n0, A, Wt + (size_t)3 * HDIM * HDIM, bias, 1.0f,
                   resid, nullptr, Of, nullptr);
}

// ============================================================= attention ===
// (r12 verbatim) 8 waves, 128 q/block; wave (qt,kvh): 32q x 32kv-half.
// 3 LDS buffers (48 KB), ONE barrier/tile:
//   vmcnt(0) -> barrier -> stage(t+2) -> QK(t+1) || exp/pack(t) -> PV(t)
__global__ __launch_bounds__(512)
void attn_kernel(const __bf16* __restrict__ Qb, const __bf16* __restrict__ Kb,
                 const __bf16* __restrict__ Vtg, const unsigned* __restrict__ mbH,
                 __bf16* __restrict__ AO)
{
  __shared__ __align__(16) char smem[49152];
  __bf16 (*Ks)[64][64] = (__bf16(*)[64][64])smem;            // 3 x 8 KB
  __bf16 (*Vt)[64][64] = (__bf16(*)[64][64])(smem + 24576);  // 3 x 8 KB

  const int bh = blockIdx.x, b = bh >> 4, h = bh & 15;
  const int tid = threadIdx.x, lane = tid & 63, w = tid >> 6;
  const int fr = lane & 31, hi = lane >> 5;
  const int qt = w >> 1, kvh = w & 1;
  const int qw = blockIdx.y * 128 + qt * 32;
  const int q  = qw + fr;

  bf16x8 qf[4];
  #pragma unroll
  for (int st = 0; st < 4; ++st)
    qf[st] = *(const bf16x8*)&Qb[((size_t)b * S_LEN + q) * HDIM + h * HEADD + st * 16 + hi * 8];

  const int srl = w * 8 + (lane >> 3);
  const int ssw = ((lane & 7) ^ (srl & 7)) * 8;
  const __bf16* ksrc = Kb  + ((size_t)b * S_LEN + srl) * HDIM + h * HEADD + ssw;
  const __bf16* vsrc = Vtg + ((size_t)bh * HEADD + srl) * S_LEN + ssw;
  const unsigned* tbl = mbH + ((size_t)(hi * 2 + b) * 32) * S_LEN + q;

  bf16x8 ones;
  #pragma unroll
  for (int e = 0; e < 8; ++e) ones[e] = (__bf16)1.0f;

  f32x16 o0 = {}, o1 = {}, l_acc = {};

  unsigned mv  = tbl[0];
  unsigned nmA = tbl[S_LEN];
  unsigned nmB = 0;
  gload16(ksrc,             (void*)&Ks[0][w * 8][0]);
  gload16(vsrc,             (void*)&Vt[0][w * 8][0]);
  gload16(ksrc + 64 * HDIM, (void*)&Ks[1][w * 8][0]);
  gload16(vsrc + 64,        (void*)&Vt[1][w * 8][0]);
  asm volatile("s_waitcnt vmcnt(2)" ::: "memory");
  __builtin_amdgcn_s_barrier();

  f32x16 s_cur = {};
  {
    const __bf16* Kb0 = &Ks[0][0][0];
    #pragma unroll
    for (int st = 0; st < 4; ++st)
      s_cur = __builtin_amdgcn_mfma_f32_32x32x16_bf16(
          lds_rdS<128>(Kb0, kvh * 32 + fr, st * 32 + hi * 16), qf[st], s_cur, 0, 0, 0);
  }

  int c0 = 0, c1 = 1, c2 = 2;
  for (int t = 0; t < 32; ++t) {
    asm volatile("s_waitcnt vmcnt(0)" ::: "memory");
    __builtin_amdgcn_s_barrier();
    __builtin_amdgcn_sched_barrier(0);

    if (t < 30) {
      gload16(ksrc + (size_t)(t + 2) * 64 * HDIM, (void*)&Ks[c2][w * 8][0]);
      gload16(vsrc + (size_t)(t + 2) * 64,        (void*)&Vt[c2][w * 8][0]);
      nmB = tbl[(size_t)(t + 2) * S_LEN];
    }

    f32x16 s_nxt = {};
    if (t < 31) {
      const __bf16* Kbn = &Ks[c1][0][0];
      __builtin_amdgcn_s_setprio(1);
      #pragma unroll
      for (int st = 0; st < 4; ++st)
        s_nxt = __builtin_amdgcn_mfma_f32_32x32x16_bf16(
            lds_rdS<128>(Kbn, kvh * 32 + fr, st * 32 + hi * 16), qf[st], s_nxt, 0, 0, 0);
      __builtin_amdgcn_s_setprio(0);
    }

    float pp[16];
    #pragma unroll
    for (int j = 0; j < 16; ++j) {
      const float e = __builtin_amdgcn_exp2f(s_cur[j]);
      const unsigned a = (unsigned)__builtin_amdgcn_sbfe(mv, j + 16 * kvh, 1);
      pp[j] = __uint_as_float(a & __float_as_uint(e));
    }
    bf16x8 pa[2];
    #pragma unroll
    for (int g = 0; g < 2; ++g) {
      const int o = g * 8;
      unsigned x  = cvtpk_bf16(pp[o + 0], pp[o + 1]);
      unsigned x2 = cvtpk_bf16(pp[o + 2], pp[o + 3]);
      unsigned y  = cvtpk_bf16(pp[o + 4], pp[o + 5]);
      unsigned y2 = cvtpk_bf16(pp[o + 6], pp[o + 7]);
      plswap(x, y);
      plswap(x2, y2);
      union { unsigned u[4]; bf16x8 v; } uu;
      uu.u[0] = x; uu.u[1] = x2; uu.u[2] = y; uu.u[3] = y2;
      pa[g] = uu.v;
    }

    {
      const __bf16* Vbc = &Vt[c0][0][0];
      __builtin_amdgcn_s_setprio(1);
      #pragma unroll
      for (int g = 0; g < 2; ++g) {
        const int bcol = kvh * 64 + g * 32 + hi * 16;
        l_acc = __builtin_amdgcn_mfma_f32_32x32x16_bf16(pa[g], ones, l_acc, 0, 0, 0);
        o0 = __builtin_amdgcn_mfma_f32_32x32x16_bf16(
            pa[g], lds_rdS<128>(Vbc, fr,      bcol), o0, 0, 0, 0);
        o1 = __builtin_amdgcn_mfma_f32_32x32x16_bf16(
            pa[g], lds_rdS<128>(Vbc, 32 + fr, bcol), o1, 0, 0, 0);
      }
      __builtin_amdgcn_s_setprio(0);
    }

    mv = nmA; nmA = nmB;
    s_cur = s_nxt;
    const int tmp = c0; c0 = c1; c1 = c2; c2 = tmp;
  }

  __builtin_amdgcn_s_barrier();
  float* sh = (float*)smem;
  const int li = qt * 64 + lane;
  if (kvh) {
    #pragma unroll
    for (int j = 0; j < 16; ++j) {
      sh[(j)      * 256 + li] = o0[j];
      sh[(16 + j) * 256 + li] = o1[j];
      sh[(32 + j) * 256 + li] = l_acc[j];
    }
  }
  __builtin_amdgcn_s_barrier();
  if (!kvh) {
    #pragma unroll
    for (int g = 0; g < 4; ++g) {
      #pragma unroll
      for (int r = 0; r < 4; ++r) {
        const int j = g * 4 + r;
        const float inv = __builtin_amdgcn_rcpf(l_acc[j] + sh[(32 + j) * 256 + li]);
        const int qq = qw + g * 8 + hi * 4 + r;
        AO[((size_t)b * S_LEN + qq) * HDIM + h * HEADD + fr]      =
            (__bf16)((o0[j] + sh[(j) * 256 + li]) * inv);
        AO[((size_t)b * S_LEN + qq) * HDIM + h * HEADD + 32 + fr] =
            (__bf16)((o1[j] + sh[(16 + j) * 256 + li]) * inv);
      }
    }
  }
}

// ============================================================= layernorm ===
__global__ __launch_bounds__(256)
void ln_kernel(float* __restrict__ y, const float* __restrict__ gamma,
               const float* __restrict__ beta)
{
  __shared__ float red[8];
  const int tid = threadIdx.x;
  float* p = y + (size_t)blockIdx.x * HDIM;

  float4 vv = *(const float4*)&p[tid * 4];
  float s  = vv.x + vv.y + vv.z + vv.w;
  float ss = vv.x * vv.x + vv.y * vv.y + vv.z * vv.z + vv.w * vv.w;
  #pragma unroll
  for (int d = 1; d < 64; d <<= 1) {
    s  += __shfl_xor(s, d);
    ss += __shfl_xor(ss, d);
  }
  const int wid = tid >> 6;
  if ((tid & 63) == 0) { red[wid * 2] = s; red[wid * 2 + 1] = ss; }
  __syncthreads();
  s  = red[0] + red[2] + red[4] + red[6];
  ss = red[1] + red[3] + red[5] + red[7];
  const float mean = s * (1.0f / HDIM);
  const float var  = ss * (1.0f / HDIM) - mean * mean;
  const float inv  = rsqrtf(var + 1e-5f);

  const float4 g  = *(const float4*)&gamma[tid * 4];
  const float4 bt = *(const float4*)&beta[tid * 4];
  vv.x = (vv.x - mean) * inv * g.x + bt.x;
  vv.y = (vv.y - mean) * inv * g.y + bt.y;
  vv.z = (vv.z - mean) * inv * g.z + bt.z;
  vv.w = (vv.w - mean) * inv * g.w + bt.w;
  *(float4*)&p[tid * 4] = vv;
}

// ================================================================ launch ===
extern "C" void kernel_launch(void* const* d_in, const int* in_sizes, int n_in,
                              void* d_out, int out_size, void* d_ws, size_t ws_size,
                              hipStream_t stream) {
  const float* q     = (const float*)d_in[0];
  const float* k     = (const float*)d_in[1];
  const float* v     = (const float*)d_in[2];
  const int*   mask  = (const int*)  d_in[3];
  const float* Wq    = (const float*)d_in[4];
  const float* bq    = (const float*)d_in[5];
  const float* Wk    = (const float*)d_in[6];
  const float* bk    = (const float*)d_in[7];
  const float* Wv    = (const float*)d_in[8];
  const float* bv    = (const float*)d_in[9];
  const float* Wfc   = (const float*)d_in[10];
  const float* bfc   = (const float*)d_in[11];
  const float* gamma = (const float*)d_in[12];
  const float* beta  = (const float*)d_in[13];
  float* out = (float*)d_out;

  char* ws = (char*)d_ws;
  const size_t MB16 = (size_t)MTOT * HDIM * 2;     // 8.39 MB per bf16 matrix
  unsigned* mbH = (unsigned*)ws;                   // 1 MB
  __bf16* Wt  = (__bf16*)(ws + (1u << 20));        // 8 MB
  __bf16* Qc  = (__bf16*)(ws + (1u << 20) + 4 * (size_t)HDIM * HDIM * 2);
  __bf16* Kc  = (__bf16*)((char*)Qc + MB16);
  __bf16* Vc  = (__bf16*)((char*)Kc + MB16);
  __bf16* Qb  = (__bf16*)((char*)Vc + MB16);
  __bf16* Kb  = (__bf16*)((char*)Qb + MB16);
  __bf16* Vtg = (__bf16*)((char*)Kb + MB16);       // V^T written by qkv z=2
  __bf16* AO  = Kc;   // alias: Kc dead after qkv

  const dim3 blk(256);

  prologue_kernel<<<dim3(39936), blk, 0, stream>>>(
      q, k, v, mask, Wq, Wk, Wv, Wfc, Qc, Kc, Vc, mbH, Wt);

  qkv_kernel<<<dim3(768), blk, 0, stream>>>(
      Qc, Kc, Vc, Wt, bq, bk, bv, Qb, Kb, Vtg);

  attn_kernel<<<dim3(BATCH * NHEADS, S_LEN / 128), dim3(512), 0, stream>>>(
      Qb, Kb, Vtg, mbH, AO);

  fc_kernel<<<dim3(8, 64), blk, 0, stream>>>(
      AO, Wt, bfc, q, out);

  ln_kernel<<<dim3(MTOT), blk, 0, stream>>>(out, gamma, beta);
}